// Round 1
// baseline (569.224 us; speedup 1.0000x reference)
//
#include <hip/hip_runtime.h>
#include <hip/hip_bf16.h>

#define B_ROWS 131072
#define TPB 256
#define CHUNKS 8

// fp32 value of 2*pi (matches XLA's f32 constant)
#define TWO_PI_F 6.28318530717958647692f

// Output layout (element offsets into d_out, all float32):
//   model_output            [131072,3]   @ 0
//   top_outputs             [131072,1,3] @ 393216
//   selection_indices       [131072]     @ 786432   (written as float values)
//   selection_logits        [131072,64]  @ 917504   (all 1.0f)
//   selection_probabilities [131072,64]  @ 9306112  (all 1/64)
#define OUT_TOP    393216
#define OUT_SEL    786432
#define OUT_LOGITS 917504
#define OUT_PROBS  9306112

// LDS weight layout (floats):
// 0: W0[64][6]=384 | 384: b0[64] | 448: W1[64][64] | 4544: b1 | 4608: W2 | 8704: b2
// 8768: W3 | 12864: b3 | 12928: W4[3][64]=192 | 13120: b4[3]
#define L_W0 0
#define L_B0 384
#define L_W1 448
#define L_B1 4544
#define L_W2 4608
#define L_B2 8704
#define L_W3 8768
#define L_B3 12864
#define L_W4 12928
#define L_B4 13120
#define L_TOT 13124

__global__ void k_prep(const float* __restrict__ in, float* __restrict__ sel_f,
                       int* __restrict__ sel, int* __restrict__ counts) {
    __shared__ int hist[64];
    const int tid = threadIdx.x;
    if (tid < 64) hist[tid] = 0;
    __syncthreads();
    const int stride = gridDim.x * blockDim.x;
    for (int r = blockIdx.x * blockDim.x + tid; r < B_ROWS; r += stride) {
        float x0 = in[r * 6 + 0];
        float x2 = in[r * 6 + 2];
        float a = atan2f(x2, x0);
        a = fmodf(a + TWO_PI_F, TWO_PI_F);
        float t = a / TWO_PI_F * 64.0f;
        int s = (int)floorf(t);
        s = s < 0 ? 0 : (s > 63 ? 63 : s);
        sel[r] = s;
        sel_f[r] = (float)s;
        atomicAdd(&hist[s], 1);
    }
    __syncthreads();
    if (tid < 64) atomicAdd(&counts[tid], hist[tid]);
}

__global__ void k_scan(const int* __restrict__ counts, int* __restrict__ offsets,
                       int* __restrict__ cursor) {
    __shared__ int sh[64];
    const int t = threadIdx.x;  // 64 threads
    const int c = counts[t];
    sh[t] = c;
    __syncthreads();
    int sum = 0;
    for (int j = 0; j < t; ++j) sum += sh[j];
    offsets[t] = sum;
    cursor[t] = sum;
    if (t == 63) offsets[64] = sum + c;
}

__global__ void k_scatter(const int* __restrict__ sel, int* __restrict__ cursor,
                          int* __restrict__ rowsArr) {
    const int stride = gridDim.x * blockDim.x;
    for (int r = blockIdx.x * blockDim.x + threadIdx.x; r < B_ROWS; r += stride) {
        const int s = sel[r];
        const int pos = atomicAdd(&cursor[s], 1);
        rowsArr[pos] = r;
    }
}

__global__ __launch_bounds__(TPB, 2) void k_mlp(
    const float* __restrict__ in,
    const float* __restrict__ w0, const float* __restrict__ b0,
    const float* __restrict__ w1, const float* __restrict__ b1,
    const float* __restrict__ w2, const float* __restrict__ b2,
    const float* __restrict__ w3, const float* __restrict__ b3,
    const float* __restrict__ w4, const float* __restrict__ b4,
    const int* __restrict__ offsets, const int* __restrict__ rowsArr,
    float* __restrict__ out) {
    __shared__ float lds[L_TOT];
    const int m = blockIdx.x / CHUNKS;
    const int chunk = blockIdx.x % CHUNKS;
    const int tid = threadIdx.x;

    // ---- fused constant fills: selection_logits = 1.0, probabilities = 1/64 ----
    {
        const int gtid = blockIdx.x * TPB + tid;  // 0..131071 (grid is exactly 512x256)
        float4* logits = (float4*)(out + OUT_LOGITS);
        float4* probs = (float4*)(out + OUT_PROBS);
        const float4 ones = make_float4(1.f, 1.f, 1.f, 1.f);
        const float4 pr = make_float4(0.015625f, 0.015625f, 0.015625f, 0.015625f);
#pragma unroll
        for (int k = 0; k < 16; ++k) {
            logits[gtid + k * B_ROWS] = ones;
            probs[gtid + k * B_ROWS] = pr;
        }
    }

    // ---- stage this model's weights into LDS (float4, all offsets 16B-aligned) ----
    {
        const float* srcs[9] = {w0 + m * 384, b0 + m * 64, w1 + m * 4096,
                                b1 + m * 64,  w2 + m * 4096, b2 + m * 64,
                                w3 + m * 4096, b3 + m * 64, w4 + m * 192};
        const int sz4[9] = {96, 16, 1024, 16, 1024, 16, 1024, 16, 48};
        const int dst[9] = {L_W0, L_B0, L_W1, L_B1, L_W2, L_B2, L_W3, L_B3, L_W4};
        for (int a = 0; a < 9; ++a) {
            const float4* s = (const float4*)srcs[a];
            float4* d = (float4*)(lds + dst[a]);
            const int n4 = sz4[a];
            for (int k = tid; k < n4; k += TPB) d[k] = s[k];
        }
        if (tid < 3) lds[L_B4 + tid] = b4[m * 3 + tid];
    }
    __syncthreads();

    const int start = offsets[m];
    const int end = offsets[m + 1];

    for (int rr = start + chunk * TPB + tid; rr < end; rr += CHUNKS * TPB) {
        const int row = rowsArr[rr];
        const float* xin = in + row * 6;
        const float x0 = xin[0], x1 = xin[1], x2 = xin[2];
        const float x3 = xin[3], x4 = xin[4], x5 = xin[5];

        float h[64];
        // ---- layer 0: 6 -> 64, relu ----
#pragma unroll
        for (int o = 0; o < 64; ++o) {
            const float* w = lds + L_W0 + o * 6;
            float acc = lds[L_B0 + o];
            acc = fmaf(w[0], x0, acc);
            acc = fmaf(w[1], x1, acc);
            acc = fmaf(w[2], x2, acc);
            acc = fmaf(w[3], x3, acc);
            acc = fmaf(w[4], x4, acc);
            acc = fmaf(w[5], x5, acc);
            h[o] = fmaxf(acc, 0.f);
        }

        // ---- layers 1..3: 64 -> 64, relu ----
#pragma unroll 1
        for (int l = 0; l < 3; ++l) {
            const float* wl = lds + L_W1 + l * 4160;  // 4096 W + 64 b per layer
            const float* bl = wl + 4096;
            float g[64];
#pragma unroll
            for (int o = 0; o < 64; ++o) {
                float acc = bl[o];
                const float4* wr = (const float4*)(wl + o * 64);
#pragma unroll
                for (int q = 0; q < 16; ++q) {
                    const float4 wv = wr[q];
                    acc = fmaf(wv.x, h[4 * q + 0], acc);
                    acc = fmaf(wv.y, h[4 * q + 1], acc);
                    acc = fmaf(wv.z, h[4 * q + 2], acc);
                    acc = fmaf(wv.w, h[4 * q + 3], acc);
                }
                g[o] = fmaxf(acc, 0.f);
            }
#pragma unroll
            for (int o = 0; o < 64; ++o) h[o] = g[o];
        }

        // ---- layer 4: 64 -> 3, no relu ----
        float y[3];
#pragma unroll
        for (int c = 0; c < 3; ++c) {
            float acc = lds[L_B4 + c];
            const float4* wr = (const float4*)(lds + L_W4 + c * 64);
#pragma unroll
            for (int q = 0; q < 16; ++q) {
                const float4 wv = wr[q];
                acc = fmaf(wv.x, h[4 * q + 0], acc);
                acc = fmaf(wv.y, h[4 * q + 1], acc);
                acc = fmaf(wv.z, h[4 * q + 2], acc);
                acc = fmaf(wv.w, h[4 * q + 3], acc);
            }
            y[c] = acc;
        }

        out[row * 3 + 0] = y[0];
        out[row * 3 + 1] = y[1];
        out[row * 3 + 2] = y[2];
        float* top = out + OUT_TOP;
        top[row * 3 + 0] = y[0];
        top[row * 3 + 1] = y[1];
        top[row * 3 + 2] = y[2];
    }
}

extern "C" void kernel_launch(void* const* d_in, const int* in_sizes, int n_in,
                              void* d_out, int out_size, void* d_ws, size_t ws_size,
                              hipStream_t stream) {
    const float* in = (const float*)d_in[0];
    const float* w0 = (const float*)d_in[1];
    const float* b0 = (const float*)d_in[2];
    const float* w1 = (const float*)d_in[3];
    const float* b1 = (const float*)d_in[4];
    const float* w2 = (const float*)d_in[5];
    const float* b2 = (const float*)d_in[6];
    const float* w3 = (const float*)d_in[7];
    const float* b3 = (const float*)d_in[8];
    const float* w4 = (const float*)d_in[9];
    const float* b4 = (const float*)d_in[10];
    float* out = (float*)d_out;

    int* sel = (int*)d_ws;             // [131072]
    int* rowsArr = sel + B_ROWS;       // [131072]
    int* counts = rowsArr + B_ROWS;    // [64]
    int* offsets = counts + 64;        // [65]
    int* cursor = offsets + 65;        // [64]

    hipMemsetAsync(counts, 0, 64 * sizeof(int), stream);

    k_prep<<<512, TPB, 0, stream>>>(in, out + OUT_SEL, sel, counts);
    k_scan<<<1, 64, 0, stream>>>(counts, offsets, cursor);
    k_scatter<<<512, TPB, 0, stream>>>(sel, cursor, rowsArr);
    k_mlp<<<512, TPB, 0, stream>>>(in, w0, b0, w1, b1, w2, b2, w3, b3, w4, b4,
                                   offsets, rowsArr, out);
}

// Round 5
// 342.783 us; speedup vs baseline: 1.6606x; 1.6606x over previous
//
#include <hip/hip_runtime.h>
#include <hip/hip_bf16.h>

#define B_ROWS 131072
#define TWO_PI_F 6.28318530717958647692f

// Output layout (float32 element offsets into d_out):
//   model_output [131072,3] @0 | top_outputs @393216 | selection_indices @786432
//   selection_logits @917504 (1.0f) | selection_probabilities @9306112 (1/64)
#define OUT_TOP    393216
#define OUT_SEL    786432
#define OUT_LOGITS 917504
#define OUT_PROBS  9306112

// Workspace layout (int32 element offsets):
#define WS_SEL    0          // sel[131072]
#define WS_BLK    131072     // per-block hist / scatter bases [512*64]
#define WS_ROWS   163840     // padded rowsArr[135168], memset to -1
#define WS_GMOD   299008     // groupModel[2112], memset to -1
#define NGRP_MAX  2112

typedef float vfloat4 __attribute__((ext_vector_type(4)));

__device__ __forceinline__ float rl(float v, int lane) {
    return __int_as_float(__builtin_amdgcn_readlane(__float_as_int(v), lane));
}

// ---------------- k_prep: selection + per-block hist + constant fills ----------------
__global__ __launch_bounds__(256) void k_prep(const float* __restrict__ in,
                                              float* __restrict__ out,
                                              int* __restrict__ sel,
                                              int* __restrict__ blkCnt) {
    __shared__ int hist[64];
    const int tid = threadIdx.x, bid = blockIdx.x;
    if (tid < 64) hist[tid] = 0;
    __syncthreads();

    const int r = bid * 256 + tid;  // grid is exactly 512x256 = 131072
    const float xx = in[r * 6 + 0];
    const float zz = in[r * 6 + 2];
    float a = atan2f(zz, xx);
    a = fmodf(a + TWO_PI_F, TWO_PI_F);
    const float t = a / TWO_PI_F * 64.0f;   // keep exact op order (boundary-sensitive)
    int s = (int)floorf(t);
    s = s < 0 ? 0 : (s > 63 ? 63 : s);
    sel[r] = s;
    out[OUT_SEL + r] = (float)s;
    atomicAdd(&hist[s], 1);

    // constant fills, nontemporal (no L2 pollution / no write-allocate fetch)
    {
        vfloat4* lg = (vfloat4*)(out + OUT_LOGITS);
        vfloat4* pb = (vfloat4*)(out + OUT_PROBS);
        const vfloat4 ones = {1.f, 1.f, 1.f, 1.f};
        const vfloat4 pr = {0.015625f, 0.015625f, 0.015625f, 0.015625f};
#pragma unroll
        for (int k = 0; k < 16; ++k) {
            __builtin_nontemporal_store(ones, lg + r + k * B_ROWS);
            __builtin_nontemporal_store(pr, pb + r + k * B_ROWS);
        }
    }

    __syncthreads();
    if (tid < 64) blkCnt[bid * 64 + tid] = hist[tid];
}

// ---------------- k_scan: model totals -> padded offsets, per-block bases, group map ----
__global__ void k_scan(int* __restrict__ blkCnt, int* __restrict__ gmodel) {
    const int m = threadIdx.x;  // 64 threads
    int tot = 0;
    for (int b = 0; b < 512; ++b) tot += blkCnt[b * 64 + m];
    const int grp = (tot + 63) >> 6;

    __shared__ int shP[64], shG[64];
    shP[m] = grp << 6;
    shG[m] = grp;
    __syncthreads();
    int offP = 0, offG = 0;
    for (int j = 0; j < m; ++j) { offP += shP[j]; offG += shG[j]; }

    int run = offP;  // padded base for model m
    for (int b = 0; b < 512; ++b) {
        const int c = blkCnt[b * 64 + m];
        blkCnt[b * 64 + m] = run;   // becomes this block's scatter base for model m
        run += c;
    }
    for (int i = 0; i < grp; ++i) gmodel[offG + i] = m;
}

// ---------------- k_scatter: no global atomics, per-block reserved ranges ----------------
__global__ __launch_bounds__(256) void k_scatter(const int* __restrict__ sel,
                                                 const int* __restrict__ blkBase,
                                                 int* __restrict__ rowsArr) {
    __shared__ int cur[64];
    const int tid = threadIdx.x, bid = blockIdx.x;
    if (tid < 64) cur[tid] = blkBase[bid * 64 + tid];
    __syncthreads();
    const int r = bid * 256 + tid;
    const int s = sel[r];
    const int pos = atomicAdd(&cur[s], 1);
    rowsArr[pos] = r;
}

// ---------------- k_mlp_rl: 1 wave per 64-row group; weights in VGPRs + readlane ----------
__global__ __launch_bounds__(64, 2) void k_mlp_rl(
    const float* __restrict__ in,
    const float* __restrict__ w0, const float* __restrict__ b0,
    const float* __restrict__ w1, const float* __restrict__ b1,
    const float* __restrict__ w2, const float* __restrict__ b2,
    const float* __restrict__ w3, const float* __restrict__ b3,
    const float* __restrict__ w4, const float* __restrict__ b4,
    const int* __restrict__ gmodel, const int* __restrict__ rowsArr,
    float* __restrict__ out) {
    const int m = gmodel[blockIdx.x];
    if (m < 0) return;  // unused tail wave
    const int lane = threadIdx.x;
    __shared__ float stage[64 * 66];      // per-lane runtime-indexed g staging
    float* myst = stage + lane * 66;

    const int row = rowsArr[blockIdx.x * 64 + lane];
    const bool valid = row >= 0;
    const int r = valid ? row : 0;

    const float* xin = in + r * 6;
    const float x0 = xin[0], x1 = xin[1], x2 = xin[2];
    const float x3 = xin[3], x4 = xin[4], x5 = xin[5];

    // ---- layer 0: 6 -> 64 (lane l holds W0[l][0..5]) ----
    {
        const float* W0 = w0 + m * 384 + lane * 6;
        const float wa0 = W0[0], wa1 = W0[1], wa2 = W0[2];
        const float wa3 = W0[3], wa4 = W0[4], wa5 = W0[5];
        const float bv = b0[m * 64 + lane];
#pragma unroll 2
        for (int o = 0; o < 64; ++o) {
            float a = rl(bv, o);
            a = fmaf(rl(wa0, o), x0, a);
            a = fmaf(rl(wa1, o), x1, a);
            a = fmaf(rl(wa2, o), x2, a);
            a = fmaf(rl(wa3, o), x3, a);
            a = fmaf(rl(wa4, o), x4, a);
            a = fmaf(rl(wa5, o), x5, a);
            myst[o] = fmaxf(a, 0.f);
        }
    }

    // ---- layers 1..3: 64 -> 64 (lane l holds W[l][0..63] in 16 float4) ----
#pragma unroll 1
    for (int l = 0; l < 3; ++l) {
        const float* Wl = (l == 0 ? w1 : l == 1 ? w2 : w3) + m * 4096;
        const float* blp = (l == 0 ? b1 : l == 1 ? b2 : b3) + m * 64;
        float4 wq[16];
        const float4* Wr = (const float4*)(Wl + lane * 64);
#pragma unroll
        for (int q = 0; q < 16; ++q) wq[q] = Wr[q];
        const float bv = blp[lane];

        float h[64];
#pragma unroll
        for (int j = 0; j < 32; ++j) {
            const float2 t = *(const float2*)(myst + 2 * j);
            h[2 * j] = t.x;
            h[2 * j + 1] = t.y;
        }
#pragma unroll 2
        for (int o = 0; o < 64; ++o) {
            float a = rl(bv, o);
#pragma unroll
            for (int q = 0; q < 16; ++q) {
                const float4 wv = wq[q];
                a = fmaf(rl(wv.x, o), h[4 * q + 0], a);
                a = fmaf(rl(wv.y, o), h[4 * q + 1], a);
                a = fmaf(rl(wv.z, o), h[4 * q + 2], a);
                a = fmaf(rl(wv.w, o), h[4 * q + 3], a);
            }
            myst[o] = fmaxf(a, 0.f);
        }
    }

    // ---- layer 4: 64 -> 3 (lane l holds column l of W4) ----
    {
        float h[64];
#pragma unroll
        for (int j = 0; j < 32; ++j) {
            const float2 t = *(const float2*)(myst + 2 * j);
            h[2 * j] = t.x;
            h[2 * j + 1] = t.y;
        }
        const float c0 = w4[m * 192 + lane];
        const float c1 = w4[m * 192 + 64 + lane];
        const float c2 = w4[m * 192 + 128 + lane];
        const float b4v = (lane < 3) ? b4[m * 3 + lane] : 0.f;
        float y0 = rl(b4v, 0), y1 = rl(b4v, 1), y2 = rl(b4v, 2);
#pragma unroll
        for (int k = 0; k < 64; ++k) {
            y0 = fmaf(rl(c0, k), h[k], y0);
            y1 = fmaf(rl(c1, k), h[k], y1);
            y2 = fmaf(rl(c2, k), h[k], y2);
        }
        if (valid) {
            out[row * 3 + 0] = y0;
            out[row * 3 + 1] = y1;
            out[row * 3 + 2] = y2;
            float* top = out + OUT_TOP;
            top[row * 3 + 0] = y0;
            top[row * 3 + 1] = y1;
            top[row * 3 + 2] = y2;
        }
    }
}

extern "C" void kernel_launch(void* const* d_in, const int* in_sizes, int n_in,
                              void* d_out, int out_size, void* d_ws, size_t ws_size,
                              hipStream_t stream) {
    const float* in = (const float*)d_in[0];
    const float* w0 = (const float*)d_in[1];
    const float* b0 = (const float*)d_in[2];
    const float* w1 = (const float*)d_in[3];
    const float* b1 = (const float*)d_in[4];
    const float* w2 = (const float*)d_in[5];
    const float* b2 = (const float*)d_in[6];
    const float* w3 = (const float*)d_in[7];
    const float* b3 = (const float*)d_in[8];
    const float* w4 = (const float*)d_in[9];
    const float* b4 = (const float*)d_in[10];
    float* out = (float*)d_out;
    int* ws = (int*)d_ws;

    int* sel = ws + WS_SEL;
    int* blkCnt = ws + WS_BLK;
    int* rowsArr = ws + WS_ROWS;
    int* gmodel = ws + WS_GMOD;

    // rowsArr (135168) + gmodel (2112) -> -1
    (void)hipMemsetAsync(rowsArr, 0xFF, (135168 + NGRP_MAX) * sizeof(int), stream);

    k_prep<<<512, 256, 0, stream>>>(in, out, sel, blkCnt);
    k_scan<<<1, 64, 0, stream>>>(blkCnt, gmodel);
    k_scatter<<<512, 256, 0, stream>>>(sel, blkCnt, rowsArr);
    k_mlp_rl<<<NGRP_MAX, 64, 0, stream>>>(in, w0, b0, w1, b1, w2, b2, w3, b3,
                                          w4, b4, gmodel, rowsArr, out);
}